// Round 10
// baseline (6089.135 us; speedup 1.0000x reference)
//
#include <hip/hip_runtime.h>

constexpr int B = 32, N = 325, E = 64, S = 12, HOPS = 3;
constexpr int BN  = B * N;          // 10400
constexpr int BNE = B * N * E;      // 665600
constexpr int PBSTR = 360;          // prob bf16 stride (11 ksteps * 32 = 352 used)
constexpr int STST = 672;           // stats slice stride (650 used, padded to 128B mult)
constexpr float SCALE_INV = 0.125f;

typedef __attribute__((ext_vector_type(8))) short short8v;
typedef __attribute__((ext_vector_type(4))) float f32x4;

__device__ inline short f2bf(float f) {
  unsigned x = __builtin_bit_cast(unsigned, f);
  return (short)((x + 0x7FFFu + ((x >> 16) & 1u)) >> 16);
}
__device__ inline float bf2f(short h) {
  unsigned x = ((unsigned)(unsigned short)h) << 16;
  return __builtin_bit_cast(float, x);
}
__device__ inline float agent_loadf(const float* p) {
  return __hip_atomic_load(p, __ATOMIC_RELAXED, __HIP_MEMORY_SCOPE_AGENT);
}

// manual grid barrier: bar[0]=counter, bar[1]=generation (both zeroed per call)
__device__ inline void grid_barrier(unsigned* bar, unsigned nblk) {
  __syncthreads();
  if (threadIdx.x == 0) {
    __threadfence();
    unsigned my = __hip_atomic_load(&bar[1], __ATOMIC_ACQUIRE, __HIP_MEMORY_SCOPE_AGENT);
    unsigned prev = __hip_atomic_fetch_add(&bar[0], 1u, __ATOMIC_ACQ_REL, __HIP_MEMORY_SCOPE_AGENT);
    if (prev == nblk - 1u) {
      __hip_atomic_store(&bar[0], 0u, __ATOMIC_RELAXED, __HIP_MEMORY_SCOPE_AGENT);
      __hip_atomic_fetch_add(&bar[1], 1u, __ATOMIC_RELEASE, __HIP_MEMORY_SCOPE_AGENT);
    } else {
      while (__hip_atomic_load(&bar[1], __ATOMIC_ACQUIRE, __HIP_MEMORY_SCOPE_AGENT) == my)
        __builtin_amdgcn_s_sleep(2);
    }
  }
  __syncthreads();
}

// ---------------- adp = softmax(relu(nv1 @ nv2^T)) ----------------
__global__ __launch_bounds__(256) void adp_kernel(const float* __restrict__ nv1,
                                                  const float* __restrict__ nv2,
                                                  float* __restrict__ adp) {
  int n = blockIdx.x;
  __shared__ float row[E];
  __shared__ float buf[N];
  __shared__ float red[256];
  int tid = threadIdx.x;
  if (tid < E) row[tid] = nv1[n * E + tid];
  __syncthreads();
  float lmax = -1e30f;
  for (int m = tid; m < N; m += 256) {
    const float* v2 = nv2 + (size_t)m * E;
    float s = 0.f;
#pragma unroll
    for (int e = 0; e < E; ++e) s += row[e] * v2[e];
    s = fmaxf(s, 0.f);
    buf[m] = s;
    lmax = fmaxf(lmax, s);
  }
  red[tid] = lmax;
  __syncthreads();
  for (int off = 128; off > 0; off >>= 1) {
    if (tid < off) red[tid] = fmaxf(red[tid], red[tid + off]);
    __syncthreads();
  }
  float mx = red[0];
  __syncthreads();
  float lsum = 0.f;
  for (int m = tid; m < N; m += 256) {
    float ev = expf(buf[m] - mx);
    buf[m] = ev;
    lsum += ev;
  }
  red[tid] = lsum;
  __syncthreads();
  for (int off = 128; off > 0; off >>= 1) {
    if (tid < off) red[tid] += red[tid + off];
    __syncthreads();
  }
  float inv = 1.f / red[0];
  for (int m = tid; m < N; m += 256) adp[(size_t)n * N + m] = buf[m] * inv;
}

// ---------------- rowmm body: out[r][e'] (+)= in[r][e] W[e][e'] ----------------
__device__ inline void rowmm_body(const float* __restrict__ in, const float* __restrict__ W,
                                  const float* __restrict__ bias, float* __restrict__ out,
                                  int accum, int blk, int nblk) {
  __shared__ float Wl[E][E + 1];
  __shared__ float rbuf[4][4][E];
  int tid = threadIdx.x, w = tid >> 6, l = tid & 63;
  for (int idx = tid; idx < E * E; idx += 256) Wl[idx >> 6][idx & 63] = W[idx];
  __syncthreads();
  float bv = bias ? bias[l] : 0.f;
  constexpr int NG = BN / 16; // 650
  for (int g = blk; g < NG; g += nblk) {
    int base = g * 16 + w * 4;
#pragma unroll
    for (int rr = 0; rr < 4; ++rr) rbuf[w][rr][l] = in[(size_t)(base + rr) * E + l];
    float acc[4];
#pragma unroll
    for (int rr = 0; rr < 4; ++rr)
      acc[rr] = accum ? out[(size_t)(base + rr) * E + l] : bv;
#pragma unroll
    for (int k = 0; k < 16; ++k) {
      float w0 = Wl[4 * k][l], w1 = Wl[4 * k + 1][l], w2 = Wl[4 * k + 2][l], w3 = Wl[4 * k + 3][l];
#pragma unroll
      for (int rr = 0; rr < 4; ++rr) {
        float4 rv = *(const float4*)&rbuf[w][rr][4 * k];
        acc[rr] += rv.x * w0 + rv.y * w1 + rv.z * w2 + rv.w * w3;
      }
    }
#pragma unroll
    for (int rr = 0; rr < 4; ++rr) out[(size_t)(base + rr) * E + l] = acc[rr];
  }
}

// 6 combos: c<3 -> kms[c]; c>=3 -> C0[h]
__global__ __launch_bounds__(256) void rowmmA_kernel(const float* __restrict__ memory,
                                                     const float* __restrict__ sent_w,
                                                     const float* __restrict__ gw,
                                                     const float* __restrict__ gb,
                                                     float* __restrict__ kms,
                                                     float* __restrict__ C0) {
  int c = blockIdx.x / 112, blk = blockIdx.x % 112;
  const float *in, *W, *bias;
  float* out;
  if (c < 3) {
    in = memory + (size_t)c * BNE; W = sent_w + (size_t)c * E * E; bias = nullptr;
    out = kms + (size_t)c * BNE;
  } else {
    int h = c - 3;
    in = memory + (size_t)(h + 1) * BNE; W = gw + (size_t)h * 7 * E * E; bias = gb + h * E;
    out = C0 + (size_t)h * BNE;
  }
  rowmm_body(in, W, bias, out, 0, blk, 112);
}

__global__ __launch_bounds__(256) void rowmmZ_kernel(const float* __restrict__ tbase,
                                                     const float* __restrict__ gw,
                                                     int chunk, float* __restrict__ Zb,
                                                     int accum) {
  int h = blockIdx.x / 224, blk = blockIdx.x % 224;
  rowmm_body(tbase + (size_t)h * BNE, gw + (size_t)h * 7 * E * E + (size_t)chunk * E * E,
             nullptr, Zb + (size_t)h * BNE, accum, blk, 224);
}

// ---------------- pack support matrix into MFMA A-fragments (hi/lo) ----------------
__global__ __launch_bounds__(64) void apack_kernel(const float* __restrict__ supports,
                                                   const float* __restrict__ adp,
                                                   short* __restrict__ ap) {
  int blk = blockIdx.x;        // a*21 + nt
  int nt = blk % 21, a = blk / 21;
  const float* A = (a < 2) ? supports + (size_t)a * N * N : adp;
  int l = threadIdx.x;
  int row = nt * 16 + (l & 15);
  int k0 = (l >> 4) * 8;
  for (int ks = 0; ks < 11; ++ks) {
    short8v hi, lo;
#pragma unroll
    for (int j = 0; j < 8; ++j) {
      int m = ks * 32 + k0 + j;
      float f = (row < N && m < N) ? A[(size_t)row * N + m] : 0.f;
      short h = f2bf(f);
      hi[j] = h;
      lo[j] = f2bf(f - bf2f(h));
    }
    size_t base = ((size_t)(blk * 11 + ks) * 2) * 512 + (size_t)l * 8;
    *(short8v*)(ap + base) = hi;
    *(short8v*)(ap + base + 512) = lo;
  }
}

// ---------------- pack (3*B) x N x E fp32 into MFMA B-fragments (hi/lo) ----------------
__global__ __launch_bounds__(64) void zpack_kernel(const float* __restrict__ Zb,
                                                   short* __restrict__ zp) {
  int idx = blockIdx.x;          // hb*4 + et
  int et = idx & 3, hb = idx >> 2;
  int l = threadIdx.x;
  int e = et * 16 + (l & 15);
  int mbase = (l >> 4) * 8;
  const float* Zp = Zb + (size_t)hb * N * E;
  for (int ks = 0; ks < 11; ++ks) {
    short8v hi, lo;
#pragma unroll
    for (int j = 0; j < 8; ++j) {
      int m = ks * 32 + mbase + j;
      float f = (m < N) ? Zp[(size_t)m * E + e] : 0.f;
      short h = f2bf(f);
      hi[j] = h;
      lo[j] = f2bf(f - bf2f(h));
    }
    size_t base = ((size_t)idx * 11 + ks) * 1024 + (size_t)l * 8;
    *(short8v*)(zp + base) = hi;
    *(short8v*)(zp + base + 512) = lo;
  }
}

// ---------------- pack whh (3E x E) into MFMA B-fragments: col=out, k=e ----------------
__global__ __launch_bounds__(64) void wpack_kernel(const float* __restrict__ whh,
                                                   short* __restrict__ wp) {
  int ot = blockIdx.x;           // 12 out-tiles
  int l = threadIdx.x;
  int out = ot * 16 + (l & 15);
  int e0 = (l >> 4) * 8;
  for (int ks = 0; ks < 2; ++ks) {
    short8v hi, lo;
#pragma unroll
    for (int j = 0; j < 8; ++j) {
      int e = ks * 32 + e0 + j;
      float f = whh[(size_t)out * E + e];
      short h = f2bf(f);
      hi[j] = h;
      lo[j] = f2bf(f - bf2f(h));
    }
    size_t base = ((size_t)(ot * 2 + ks) * 2) * 512 + (size_t)l * 8;
    *(short8v*)(wp + base) = hi;
    *(short8v*)(wp + base + 512) = lo;
  }
}

// ---------------- MFMA bmm: out[hb][n][e] = sum_m A[n][m] X[hb][m][e] ----------------
__global__ __launch_bounds__(256) void bmmM_kernel(const short* __restrict__ ap,
                                                   const short* __restrict__ xp,
                                                   float* __restrict__ out) {
  int bid = blockIdx.x;
  int x8 = bid & 7, q = bid >> 3;
  int nt = q % 21, hbhi = q / 21;
  int hb = hbhi * 8 + x8;
  int tid = threadIdx.x, w = tid >> 6, l = tid & 63;
  const short8v* apf = (const short8v*)ap;
  const short8v* xpf = (const short8v*)(xp + (((size_t)hb * 4 + w) * 11) * 1024);
  f32x4 acc = {0.f, 0.f, 0.f, 0.f};
#pragma unroll
  for (int ks = 0; ks < 11; ++ks) {
    short8v ah = apf[((nt * 11 + ks) * 2 + 0) * 64 + l];
    short8v al = apf[((nt * 11 + ks) * 2 + 1) * 64 + l];
    short8v xh = xpf[(ks * 2 + 0) * 64 + l];
    short8v xl = xpf[(ks * 2 + 1) * 64 + l];
    acc = __builtin_amdgcn_mfma_f32_16x16x32_bf16(ah, xh, acc, 0, 0, 0);
    acc = __builtin_amdgcn_mfma_f32_16x16x32_bf16(ah, xl, acc, 0, 0, 0);
    acc = __builtin_amdgcn_mfma_f32_16x16x32_bf16(al, xh, acc, 0, 0, 0);
  }
  int row = nt * 16 + (l >> 4) * 4, col = w * 16 + (l & 15);
  float* o = out + (size_t)hb * N * E;
#pragma unroll
  for (int r = 0; r < 4; ++r)
    if (row + r < N) o[(size_t)(row + r) * E + col] = acc[r];
}

// ---------------- pack key into MFMA B-fragments (hi/lo bf16 split) ----------------
__global__ __launch_bounds__(128) void kpack_kernel(const float* __restrict__ memory,
                                                    short* __restrict__ kp) {
  int idx = blockIdx.x;          // (hop*B+b)*21 + ct
  int ct = idx % 21, hb = idx / 21;
  int tid = threadIdx.x, ks = tid >> 6, l = tid & 63;
  int m = ct * 16 + (l & 15);
  int e0 = ks * 32 + (l >> 4) * 8;
  short8v hi, lo;
  if (m < N) {
    const float* p = memory + ((size_t)hb * N + m) * E + e0;
#pragma unroll
    for (int j = 0; j < 8; ++j) {
      float f = p[j];
      short h = f2bf(f);
      hi[j] = h;
      lo[j] = f2bf(f - bf2f(h));
    }
  } else {
#pragma unroll
    for (int j = 0; j < 8; ++j) { hi[j] = 0; lo[j] = 0; }
  }
  size_t base = ((size_t)idx * 2 + ks) * 1024 + (size_t)l * 8;
  *(short8v*)(kp + base) = hi;
  *(short8v*)(kp + base + 512) = lo;
}

// ================= persistent step kernel (manual grid barrier) =================
__global__ __launch_bounds__(512, 4) void step_kernel(
    const float* __restrict__ hidden,
    const float* __restrict__ kms,      // 3*BNE
    const short* __restrict__ kp,       // per-hop stride B*21*2048
    const short* __restrict__ zp,       // per-hop stride B*4*11*1024
    const float* __restrict__ C0,       // 3*BNE
    float* __restrict__ statsb,         // 36*STST, zeroed
    const float* __restrict__ gamma, const float* __restrict__ beta,
    const float* __restrict__ outw, const float* __restrict__ outb,
    const float* __restrict__ wih, const short* __restrict__ wp,
    const float* __restrict__ bih, const float* __restrict__ bhh,
    unsigned* __restrict__ bar,
    float* __restrict__ dout) {
  unsigned nblk = gridDim.x;
  int bid = blockIdx.x;
  int x8 = bid & 7, q = bid >> 3;            // XCD swizzle: same-b blocks share XCD
  int rt = q % 11, bhi = q / 11;
  int b = bhi * 8 + x8;
  int n0 = rt * 32, nrows = min(32, N - n0);
  int tid = threadIdx.x, w = tid >> 6, l = tid & 63;
  int g = l >> 4;
  size_t rowbase = (size_t)b * N + n0;

  __shared__ float uT[32][68];
  __shared__ float hT[32][68];
  __shared__ float gpreL[32][68];
  __shared__ float rowred[32][8];
  __shared__ float rmax[32], rsinv[32];
  __shared__ float pvL[32], sentL[3][32], owL[2][32];
  __shared__ __align__(16) char arenaRaw[25600];  // union: pb[32][360] bf16 | gh[32][200] f32
  short (*pb)[PBSTR] = (short (*)[PBSTR])arenaRaw;
  float (*ghL)[200] = (float (*)[200])arenaRaw;

  // init
#pragma unroll
  for (int rr = 0; rr < 4; ++rr) {
    int r = w * 4 + rr;
    hT[r][l] = (r < nrows) ? hidden[(rowbase + r) * E + l] : 0.f;
    if (l == 0) pvL[r] = 0.f;
  }
  float wi0 = wih[l], wi1 = wih[64 + l], wi2 = wih[128 + l];
  float bi0 = bih[l], bi1 = bih[64 + l], bi2 = bih[128 + l];
  float bh0 = bhh[l], bh1 = bhh[64 + l], bh2 = bhh[128 + l];
  float owv = outw[l];
  float ob = outb[0];
  __syncthreads();

  for (int t = 0; t < S; ++t) {
    // ---- finish of step t-1 (stats synced at barrier end of prev iter) ----
    if (t > 0) {
      const float* st2 = statsb + (size_t)((t - 1) * 3 + 2) * STST;
#pragma unroll
      for (int rr = 0; rr < 4; ++rr) {
        int r = w * 4 + rr, n = n0 + r;
        if (r < nrows) {
          float m = agent_loadf(&st2[n]) * (1.f / 2048.f);
          float var = agent_loadf(&st2[N + n]) * (1.f / 2048.f) - m * m;
          float rstd = rsqrtf(var + 1e-5f);
          float o = (gpreL[r][l] - m) * rstd * gamma[2 * N + n] + beta[2 * N + n];
          float tt = o * owv;
#pragma unroll
          for (int off = 32; off; off >>= 1) tt += __shfl_xor(tt, off);
          float v = ob + sentL[0][r] * owL[0][r] + sentL[1][r] * owL[1][r] + sentL[2][r] * tt;
          if (l == 0) {
            dout[((size_t)b * S + (t - 1)) * N + n] = v;
            pvL[r] = v;
          }
        }
      }
      __syncthreads();
    }
    // ---- GRU: gh = hT @ whh^T via MFMA ----
    short8v hah[2][2], hal[2][2];
    {
      int arow = l & 15, ak = g * 8;
#pragma unroll
      for (int mt = 0; mt < 2; ++mt)
#pragma unroll
        for (int ks = 0; ks < 2; ++ks) {
          const float* p = &hT[mt * 16 + arow][ks * 32 + ak];
          short8v h, lo;
#pragma unroll
          for (int j = 0; j < 8; ++j) {
            float f = p[j];
            short hh = f2bf(f);
            h[j] = hh;
            lo[j] = f2bf(f - bf2f(hh));
          }
          hah[mt][ks] = h; hal[mt][ks] = lo;
        }
    }
    const short8v* wpf = (const short8v*)wp;
#pragma unroll
    for (int i = 0; i < 3; ++i) {
      int idx = w * 3 + i;          // 24 tiles: mt*12 + ot
      int mt = idx / 12, ot = idx % 12;
      f32x4 acc = {0.f, 0.f, 0.f, 0.f};
#pragma unroll
      for (int ks = 0; ks < 2; ++ks) {
        short8v wh = wpf[((ot * 2 + ks) * 2 + 0) * 64 + l];
        short8v wl = wpf[((ot * 2 + ks) * 2 + 1) * 64 + l];
        acc = __builtin_amdgcn_mfma_f32_16x16x32_bf16(hah[mt][ks], wh, acc, 0, 0, 0);
        acc = __builtin_amdgcn_mfma_f32_16x16x32_bf16(hah[mt][ks], wl, acc, 0, 0, 0);
        acc = __builtin_amdgcn_mfma_f32_16x16x32_bf16(hal[mt][ks], wh, acc, 0, 0, 0);
      }
      int row0 = mt * 16 + g * 4, col = ot * 16 + (l & 15);
#pragma unroll
      for (int r = 0; r < 4; ++r) ghL[row0 + r][col] = acc[r];
    }
    __syncthreads();
    // gate combine
#pragma unroll
    for (int rr = 0; rr < 4; ++rr) {
      int r = w * 4 + rr;
      float hv = hT[r][l];
      float g0 = ghL[r][l] + bh0;
      float g1 = ghL[r][64 + l] + bh1;
      float g2 = ghL[r][128 + l] + bh2;
      float pv = pvL[r];
      float i0 = pv * wi0 + bi0, i1 = pv * wi1 + bi1, i2 = pv * wi2 + bi2;
      float rg = 1.f / (1.f + expf(-(i0 + g0)));
      float zg = 1.f / (1.f + expf(-(i1 + g1)));
      float nn = tanhf(i2 + rg * g2);
      float hn = (1.f - zg) * nn + zg * hv;
      if (r >= nrows) hn = 0.f;
      hT[r][l] = hn;
      uT[r][l] = hn;
    }
    __syncthreads();
    // re-zero pb pad cols (clobbered by ghL)
    for (int idx2 = tid; idx2 < 32 * (PBSTR - 336); idx2 += 512) {
      int r = idx2 / (PBSTR - 336), c = idx2 - r * (PBSTR - 336);
      pb[r][336 + c] = 0;
    }
    __syncthreads();
    // ---- hops ----
    for (int h = 0; h < 3; ++h) {
      if (h > 0) {  // bnapply of hop h-1 (stats synced via barrier)
        const float* stp = statsb + (size_t)(t * 3 + h - 1) * STST;
        const float* gm = gamma + (h - 1) * N;
        const float* bt = beta + (h - 1) * N;
#pragma unroll
        for (int rr = 0; rr < 4; ++rr) {
          int r = w * 4 + rr, n = n0 + r;
          if (r < nrows) {
            float m = agent_loadf(&stp[n]) * (1.f / 2048.f);
            float var = agent_loadf(&stp[N + n]) * (1.f / 2048.f) - m * m;
            float rstd = rsqrtf(var + 1e-5f);
            float o = (gpreL[r][l] - m) * rstd * gm[n] + bt[n];
            uT[r][l] += o;
            float tt = o * owv;
#pragma unroll
            for (int off = 32; off; off >>= 1) tt += __shfl_xor(tt, off);
            if (l == 0) owL[h - 1][r] = tt;
          }
        }
        __syncthreads();
      }
      // sentinel
      const float* kmsH = kms + (size_t)h * BNE;
#pragma unroll
      for (int rr = 0; rr < 4; ++rr) {
        int r = w * 4 + rr;
        if (r < nrows) {
          float v = uT[r][l] * kmsH[(rowbase + r) * E + l];
#pragma unroll
          for (int off = 32; off; off >>= 1) v += __shfl_xor(v, off);
          if (l == 0) sentL[h][r] = v * SCALE_INV;
        }
      }
      // A fragments from uT (hi/lo)
      short8v ah[2][2], al[2][2];
      {
        int arow = l & 15, ak = g * 8;
#pragma unroll
        for (int mt = 0; mt < 2; ++mt)
#pragma unroll
          for (int ks = 0; ks < 2; ++ks) {
            const float* p = &uT[mt * 16 + arow][ks * 32 + ak];
            short8v hh_, lo_;
#pragma unroll
            for (int j = 0; j < 8; ++j) {
              float f = p[j];
              short hh = f2bf(f);
              hh_[j] = hh;
              lo_[j] = f2bf(f - bf2f(hh));
            }
            ah[mt][ks] = hh_; al[mt][ks] = lo_;
          }
      }
      // energy
      const short8v* kpb = (const short8v*)(kp + ((size_t)h * B + b) * 21 * 2048);
      f32x4 acc0[3], acc1[3];
#pragma unroll
      for (int i = 0; i < 3; ++i) {
        acc0[i] = (f32x4){0.f, 0.f, 0.f, 0.f};
        acc1[i] = (f32x4){0.f, 0.f, 0.f, 0.f};
        int ct = w + 8 * i;
        if (ct < 21) {
          short8v bh0v = kpb[(ct * 4 + 0) * 64 + l];
          short8v bl0v = kpb[(ct * 4 + 1) * 64 + l];
          short8v bh1v = kpb[(ct * 4 + 2) * 64 + l];
          short8v bl1v = kpb[(ct * 4 + 3) * 64 + l];
          f32x4 a0 = acc0[i], a1 = acc1[i];
          a0 = __builtin_amdgcn_mfma_f32_16x16x32_bf16(ah[0][0], bh0v, a0, 0, 0, 0);
          a0 = __builtin_amdgcn_mfma_f32_16x16x32_bf16(ah[0][0], bl0v, a0, 0, 0, 0);
          a0 = __builtin_amdgcn_mfma_f32_16x16x32_bf16(al[0][0], bh0v, a0, 0, 0, 0);
          a0 = __builtin_amdgcn_mfma_f32_16x16x32_bf16(ah[0][1], bh1v, a0, 0, 0, 0);
          a0 = __builtin_amdgcn_mfma_f32_16x16x32_bf16(ah[0][1], bl1v, a0, 0, 0, 0);
          a0 = __builtin_amdgcn_mfma_f32_16x16x32_bf16(al[0][1], bh1v, a0, 0, 0, 0);
          a1 = __builtin_amdgcn_mfma_f32_16x16x32_bf16(ah[1][0], bh0v, a1, 0, 0, 0);
          a1 = __builtin_amdgcn_mfma_f32_16x16x32_bf16(ah[1][0], bl0v, a1, 0, 0, 0);
          a1 = __builtin_amdgcn_mfma_f32_16x16x32_bf16(al[1][0], bh0v, a1, 0, 0, 0);
          a1 = __builtin_amdgcn_mfma_f32_16x16x32_bf16(ah[1][1], bh1v, a1, 0, 0, 0);
          a1 = __builtin_amdgcn_mfma_f32_16x16x32_bf16(ah[1][1], bl1v, a1, 0, 0, 0);
          a1 = __builtin_amdgcn_mfma_f32_16x16x32_bf16(al[1][1], bh1v, a1, 0, 0, 0);
          acc0[i] = a0; acc1[i] = a1;
        }
      }
      // row max
      {
        float m0[4], m1[4];
#pragma unroll
        for (int r = 0; r < 4; ++r) {
          float a = -1e30f, c = -1e30f;
#pragma unroll
          for (int i = 0; i < 3; ++i)
            if (w + 8 * i < 21) { a = fmaxf(a, acc0[i][r]); c = fmaxf(c, acc1[i][r]); }
#pragma unroll
          for (int off = 1; off < 16; off <<= 1) {
            a = fmaxf(a, __shfl_xor(a, off));
            c = fmaxf(c, __shfl_xor(c, off));
          }
          m0[r] = a; m1[r] = c;
        }
        if ((l & 15) == 0) {
#pragma unroll
          for (int r = 0; r < 4; ++r) {
            rowred[g * 4 + r][w] = m0[r];
            rowred[16 + g * 4 + r][w] = m1[r];
          }
        }
      }
      __syncthreads();
      if (tid < 32) {
        float a = rowred[tid][0];
#pragma unroll
        for (int j = 1; j < 8; ++j) a = fmaxf(a, rowred[tid][j]);
        rmax[tid] = a;
      }
      __syncthreads();
      // exp + bf16 + partial sums
      {
        float mx0[4], mx1[4], s0[4], s1[4];
#pragma unroll
        for (int r = 0; r < 4; ++r) {
          mx0[r] = rmax[g * 4 + r]; mx1[r] = rmax[16 + g * 4 + r];
          s0[r] = 0.f; s1[r] = 0.f;
        }
#pragma unroll
        for (int i = 0; i < 3; ++i) {
          int ct = w + 8 * i;
          if (ct < 21) {
            int col = ct * 16 + (l & 15);
            bool valid = col < N;
#pragma unroll
            for (int r = 0; r < 4; ++r) {
              short pv0 = 0, pv1 = 0;
              if (valid) {
                pv0 = f2bf(expf((acc0[i][r] - mx0[r]) * SCALE_INV));
                pv1 = f2bf(expf((acc1[i][r] - mx1[r]) * SCALE_INV));
                s0[r] += bf2f(pv0);
                s1[r] += bf2f(pv1);
              }
              pb[g * 4 + r][col] = pv0;
              pb[16 + g * 4 + r][col] = pv1;
            }
          }
        }
#pragma unroll
        for (int r = 0; r < 4; ++r) {
#pragma unroll
          for (int off = 1; off < 16; off <<= 1) {
            s0[r] += __shfl_xor(s0[r], off);
            s1[r] += __shfl_xor(s1[r], off);
          }
        }
        if ((l & 15) == 0) {
#pragma unroll
          for (int r = 0; r < 4; ++r) {
            rowred[g * 4 + r][w] = s0[r];
            rowred[16 + g * 4 + r][w] = s1[r];
          }
        }
      }
      __syncthreads();
      if (tid < 32) {
        float s = 0.f;
#pragma unroll
        for (int j = 0; j < 8; ++j) s += rowred[tid][j];
        rsinv[tid] = 1.f / s;
      }
      __syncthreads();
      // PV
      int mt2 = w >> 2, et = w & 3;
      const short8v* zpb = (const short8v*)(zp + ((size_t)h * B + b) * 4 * 11 * 1024);
      f32x4 acc = {0.f, 0.f, 0.f, 0.f};
      {
        int arow = mt2 * 16 + (l & 15), ak = g * 8;
#pragma unroll
        for (int ks = 0; ks < 11; ++ks) {
          short8v a = *(const short8v*)&pb[arow][ks * 32 + ak];
          short8v zh = zpb[((et * 11 + ks) * 2 + 0) * 64 + l];
          short8v zl = zpb[((et * 11 + ks) * 2 + 1) * 64 + l];
          acc = __builtin_amdgcn_mfma_f32_16x16x32_bf16(a, zh, acc, 0, 0, 0);
          acc = __builtin_amdgcn_mfma_f32_16x16x32_bf16(a, zl, acc, 0, 0, 0);
        }
      }
      // epilogue: gpreL + stats atomics
      const float* C0h = C0 + (size_t)h * BNE;
      float* stc = statsb + (size_t)(t * 3 + h) * STST;
      int colA = et * 16 + (l & 15);
#pragma unroll
      for (int r = 0; r < 4; ++r) {
        int row = mt2 * 16 + g * 4 + r;
        float sval = 0.f, qval = 0.f;
        if (row < nrows) {
          size_t gi = (rowbase + row) * E + colA;
          float gA = acc[r] * rsinv[row] + C0h[gi];
          gpreL[row][colA] = gA;
          sval = gA; qval = gA * gA;
        }
#pragma unroll
        for (int off = 1; off < 16; off <<= 1) {
          sval += __shfl_xor(sval, off);
          qval += __shfl_xor(qval, off);
        }
        if ((l & 15) == 0 && row < nrows) {
          atomicAdd(&stc[n0 + row], sval);
          atomicAdd(&stc[N + n0 + row], qval);
        }
      }
      grid_barrier(bar, nblk);
    }
  }
  // ---- final finish (t = S-1) ----
  {
    const float* st2 = statsb + (size_t)((S - 1) * 3 + 2) * STST;
#pragma unroll
    for (int rr = 0; rr < 4; ++rr) {
      int r = w * 4 + rr, n = n0 + r;
      if (r < nrows) {
        float m = agent_loadf(&st2[n]) * (1.f / 2048.f);
        float var = agent_loadf(&st2[N + n]) * (1.f / 2048.f) - m * m;
        float rstd = rsqrtf(var + 1e-5f);
        float o = (gpreL[r][l] - m) * rstd * gamma[2 * N + n] + beta[2 * N + n];
        float tt = o * owv;
#pragma unroll
        for (int off = 32; off; off >>= 1) tt += __shfl_xor(tt, off);
        float v = ob + sentL[0][r] * owL[0][r] + sentL[1][r] * owL[1][r] + sentL[2][r] * tt;
        if (l == 0) dout[((size_t)b * S + (S - 1)) * N + n] = v;
      }
    }
  }
}

extern "C" void kernel_launch(void* const* d_in, const int* in_sizes, int n_in,
                              void* d_out, int out_size, void* d_ws, size_t ws_size,
                              hipStream_t stream) {
  const float* hidden   = (const float*)d_in[0];
  const float* supports = (const float*)d_in[1];
  const float* memory   = (const float*)d_in[3];
  const float* nv1      = (const float*)d_in[4];
  const float* nv2      = (const float*)d_in[5];
  const float* wih      = (const float*)d_in[6];
  const float* whh      = (const float*)d_in[7];
  const float* bih      = (const float*)d_in[8];
  const float* bhh      = (const float*)d_in[9];
  const float* sent_w   = (const float*)d_in[10];
  const float* gamma    = (const float*)d_in[11];
  const float* beta     = (const float*)d_in[12];
  const float* gw       = (const float*)d_in[13];
  const float* gb       = (const float*)d_in[14];
  const float* outw     = (const float*)d_in[15];
  const float* outb     = (const float*)d_in[16];
  float* out = (float*)d_out;
  float* ws  = (float*)d_ws;

  size_t o = 0;
  float* adp   = ws + o; o += 105632;
  float* kms   = ws + o; o += (size_t)3 * BNE;
  float* C0b   = ws + o; o += (size_t)3 * BNE;
  float* uni   = ws + o; o += (size_t)9 * BNE;  // Zb(3)+t1(3)+t2(3)
  float* Zb  = uni;
  float* t1b = uni + (size_t)3 * BNE;
  float* t2b = uni + (size_t)6 * BNE;
  short* kpackS = (short*)(ws + o); o += 2064384;   // 3*B*21*2*2*512 shorts
  short* zpackS = (short*)(ws + o); o += 2162688;   // 3*B*4*11*2*512 shorts
  short* apackS = (short*)(ws + o); o += 354816;    // 3*21*11*2*512 shorts
  short* wpackS = (short*)(ws + o); o += 12288;     // 12*2*2*512 shorts
  short* xp0    = (short*)(ws + o); o += 2162688;
  short* xp1    = (short*)(ws + o); o += 2162688;
  float* statsb = ws + o; o += (size_t)36 * STST;
  unsigned* bar = (unsigned*)(ws + o); o += 64;

  hipMemsetAsync(statsb, 0, sizeof(float) * 36 * STST, stream);
  hipMemsetAsync(bar, 0, sizeof(unsigned) * 64, stream);

  adp_kernel<<<N, 256, 0, stream>>>(nv1, nv2, adp);
  rowmmA_kernel<<<672, 256, 0, stream>>>(memory, sent_w, gw, gb, kms, C0b);
  kpack_kernel<<<3 * B * 21, 128, 0, stream>>>(memory, kpackS);
  apack_kernel<<<63, 64, 0, stream>>>(supports, adp, apackS);
  wpack_kernel<<<12, 64, 0, stream>>>(whh, wpackS);
  zpack_kernel<<<3 * B * 4, 64, 0, stream>>>(memory + BNE, xp0);

  for (int a = 0; a < 3; ++a) {
    const short* apA = apackS + (size_t)a * 21 * 11 * 2 * 512;
    bmmM_kernel<<<96 * 21, 256, 0, stream>>>(apA, xp0, t1b);
    rowmmZ_kernel<<<672, 256, 0, stream>>>(t1b, gw, 2 * a + 1, Zb, (a > 0) ? 1 : 0);
    zpack_kernel<<<3 * B * 4, 64, 0, stream>>>(t1b, xp1);
    bmmM_kernel<<<96 * 21, 256, 0, stream>>>(apA, xp1, t2b);
    rowmmZ_kernel<<<672, 256, 0, stream>>>(t2b, gw, 2 * a + 2, Zb, 1);
  }
  zpack_kernel<<<3 * B * 4, 64, 0, stream>>>(Zb, zpackS);

  step_kernel<<<B * 11, 512, 0, stream>>>(hidden, kms, kpackS, zpackS, C0b, statsb,
                                          gamma, beta, outw, outb, wih, wpackS,
                                          bih, bhh, bar, out);
}

// Round 11
// 3138.549 us; speedup vs baseline: 1.9401x; 1.9401x over previous
//
#include <hip/hip_runtime.h>

constexpr int B = 32, N = 325, E = 64, S = 12, HOPS = 3;
constexpr int BN  = B * N;          // 10400
constexpr int BNE = B * N * E;      // 665600
constexpr int PBSTR = 360;          // prob bf16 stride (11 ksteps * 32 = 352 used)
constexpr int STST = 672;           // stats slice stride (650 used, padded to 128B mult)
constexpr float SCALE_INV = 0.125f;

typedef __attribute__((ext_vector_type(8))) short short8v;
typedef __attribute__((ext_vector_type(4))) float f32x4;

__device__ inline short f2bf(float f) {
  unsigned x = __builtin_bit_cast(unsigned, f);
  return (short)((x + 0x7FFFu + ((x >> 16) & 1u)) >> 16);
}
__device__ inline float bf2f(short h) {
  unsigned x = ((unsigned)(unsigned short)h) << 16;
  return __builtin_bit_cast(float, x);
}
__device__ inline float agent_loadf(const float* p) {
  return __hip_atomic_load(p, __ATOMIC_RELAXED, __HIP_MEMORY_SCOPE_AGENT);
}

// group arrival: counter per (t,hop,rt); 32 b-blocks per group. RELAXED spin —
// no per-poll cache invalidation (stats reads are coherent atomic loads themselves).
__device__ inline void group_arrive(unsigned* ctr) {
  __syncthreads();                   // drains this block's stats atomics (vmcnt before barrier)
  if (threadIdx.x == 0) {
    __threadfence();
    __hip_atomic_fetch_add(ctr, 1u, __ATOMIC_RELEASE, __HIP_MEMORY_SCOPE_AGENT);
  }
}
__device__ inline void group_wait(unsigned* ctr, unsigned target) {
  if (threadIdx.x == 0) {
    while (__hip_atomic_load(ctr, __ATOMIC_RELAXED, __HIP_MEMORY_SCOPE_AGENT) < target)
      __builtin_amdgcn_s_sleep(4);
  }
  __syncthreads();
}

// ---------------- adp = softmax(relu(nv1 @ nv2^T)) ----------------
__global__ __launch_bounds__(256) void adp_kernel(const float* __restrict__ nv1,
                                                  const float* __restrict__ nv2,
                                                  float* __restrict__ adp) {
  int n = blockIdx.x;
  __shared__ float row[E];
  __shared__ float buf[N];
  __shared__ float red[256];
  int tid = threadIdx.x;
  if (tid < E) row[tid] = nv1[n * E + tid];
  __syncthreads();
  float lmax = -1e30f;
  for (int m = tid; m < N; m += 256) {
    const float* v2 = nv2 + (size_t)m * E;
    float s = 0.f;
#pragma unroll
    for (int e = 0; e < E; ++e) s += row[e] * v2[e];
    s = fmaxf(s, 0.f);
    buf[m] = s;
    lmax = fmaxf(lmax, s);
  }
  red[tid] = lmax;
  __syncthreads();
  for (int off = 128; off > 0; off >>= 1) {
    if (tid < off) red[tid] = fmaxf(red[tid], red[tid + off]);
    __syncthreads();
  }
  float mx = red[0];
  __syncthreads();
  float lsum = 0.f;
  for (int m = tid; m < N; m += 256) {
    float ev = expf(buf[m] - mx);
    buf[m] = ev;
    lsum += ev;
  }
  red[tid] = lsum;
  __syncthreads();
  for (int off = 128; off > 0; off >>= 1) {
    if (tid < off) red[tid] += red[tid + off];
    __syncthreads();
  }
  float inv = 1.f / red[0];
  for (int m = tid; m < N; m += 256) adp[(size_t)n * N + m] = buf[m] * inv;
}

// ---------------- rowmm body: out[r][e'] (+)= in[r][e] W[e][e'] ----------------
__device__ inline void rowmm_body(const float* __restrict__ in, const float* __restrict__ W,
                                  const float* __restrict__ bias, float* __restrict__ out,
                                  int accum, int blk, int nblk) {
  __shared__ float Wl[E][E + 1];
  __shared__ float rbuf[4][4][E];
  int tid = threadIdx.x, w = tid >> 6, l = tid & 63;
  for (int idx = tid; idx < E * E; idx += 256) Wl[idx >> 6][idx & 63] = W[idx];
  __syncthreads();
  float bv = bias ? bias[l] : 0.f;
  constexpr int NG = BN / 16; // 650
  for (int g = blk; g < NG; g += nblk) {
    int base = g * 16 + w * 4;
#pragma unroll
    for (int rr = 0; rr < 4; ++rr) rbuf[w][rr][l] = in[(size_t)(base + rr) * E + l];
    float acc[4];
#pragma unroll
    for (int rr = 0; rr < 4; ++rr)
      acc[rr] = accum ? out[(size_t)(base + rr) * E + l] : bv;
#pragma unroll
    for (int k = 0; k < 16; ++k) {
      float w0 = Wl[4 * k][l], w1 = Wl[4 * k + 1][l], w2 = Wl[4 * k + 2][l], w3 = Wl[4 * k + 3][l];
#pragma unroll
      for (int rr = 0; rr < 4; ++rr) {
        float4 rv = *(const float4*)&rbuf[w][rr][4 * k];
        acc[rr] += rv.x * w0 + rv.y * w1 + rv.z * w2 + rv.w * w3;
      }
    }
#pragma unroll
    for (int rr = 0; rr < 4; ++rr) out[(size_t)(base + rr) * E + l] = acc[rr];
  }
}

// 6 combos: c<3 -> kms[c]; c>=3 -> C0[h]
__global__ __launch_bounds__(256) void rowmmA_kernel(const float* __restrict__ memory,
                                                     const float* __restrict__ sent_w,
                                                     const float* __restrict__ gw,
                                                     const float* __restrict__ gb,
                                                     float* __restrict__ kms,
                                                     float* __restrict__ C0) {
  int c = blockIdx.x / 112, blk = blockIdx.x % 112;
  const float *in, *W, *bias;
  float* out;
  if (c < 3) {
    in = memory + (size_t)c * BNE; W = sent_w + (size_t)c * E * E; bias = nullptr;
    out = kms + (size_t)c * BNE;
  } else {
    int h = c - 3;
    in = memory + (size_t)(h + 1) * BNE; W = gw + (size_t)h * 7 * E * E; bias = gb + h * E;
    out = C0 + (size_t)h * BNE;
  }
  rowmm_body(in, W, bias, out, 0, blk, 112);
}

__global__ __launch_bounds__(256) void rowmmZ_kernel(const float* __restrict__ tbase,
                                                     const float* __restrict__ gw,
                                                     int chunk, float* __restrict__ Zb,
                                                     int accum) {
  int h = blockIdx.x / 224, blk = blockIdx.x % 224;
  rowmm_body(tbase + (size_t)h * BNE, gw + (size_t)h * 7 * E * E + (size_t)chunk * E * E,
             nullptr, Zb + (size_t)h * BNE, accum, blk, 224);
}

// ---------------- pack support matrix into MFMA A-fragments (hi/lo) ----------------
__global__ __launch_bounds__(64) void apack_kernel(const float* __restrict__ supports,
                                                   const float* __restrict__ adp,
                                                   short* __restrict__ ap) {
  int blk = blockIdx.x;        // a*21 + nt
  int nt = blk % 21, a = blk / 21;
  const float* A = (a < 2) ? supports + (size_t)a * N * N : adp;
  int l = threadIdx.x;
  int row = nt * 16 + (l & 15);
  int k0 = (l >> 4) * 8;
  for (int ks = 0; ks < 11; ++ks) {
    short8v hi, lo;
#pragma unroll
    for (int j = 0; j < 8; ++j) {
      int m = ks * 32 + k0 + j;
      float f = (row < N && m < N) ? A[(size_t)row * N + m] : 0.f;
      short h = f2bf(f);
      hi[j] = h;
      lo[j] = f2bf(f - bf2f(h));
    }
    size_t base = ((size_t)(blk * 11 + ks) * 2) * 512 + (size_t)l * 8;
    *(short8v*)(ap + base) = hi;
    *(short8v*)(ap + base + 512) = lo;
  }
}

// ---------------- pack (3*B) x N x E fp32 into MFMA B-fragments (hi/lo) ----------------
__global__ __launch_bounds__(64) void zpack_kernel(const float* __restrict__ Zb,
                                                   short* __restrict__ zp) {
  int idx = blockIdx.x;          // hb*4 + et
  int et = idx & 3, hb = idx >> 2;
  int l = threadIdx.x;
  int e = et * 16 + (l & 15);
  int mbase = (l >> 4) * 8;
  const float* Zp = Zb + (size_t)hb * N * E;
  for (int ks = 0; ks < 11; ++ks) {
    short8v hi, lo;
#pragma unroll
    for (int j = 0; j < 8; ++j) {
      int m = ks * 32 + mbase + j;
      float f = (m < N) ? Zp[(size_t)m * E + e] : 0.f;
      short h = f2bf(f);
      hi[j] = h;
      lo[j] = f2bf(f - bf2f(h));
    }
    size_t base = ((size_t)idx * 11 + ks) * 1024 + (size_t)l * 8;
    *(short8v*)(zp + base) = hi;
    *(short8v*)(zp + base + 512) = lo;
  }
}

// ---------------- pack whh (3E x E) into MFMA B-fragments: col=out, k=e ----------------
__global__ __launch_bounds__(64) void wpack_kernel(const float* __restrict__ whh,
                                                   short* __restrict__ wp) {
  int ot = blockIdx.x;           // 12 out-tiles
  int l = threadIdx.x;
  int out = ot * 16 + (l & 15);
  int e0 = (l >> 4) * 8;
  for (int ks = 0; ks < 2; ++ks) {
    short8v hi, lo;
#pragma unroll
    for (int j = 0; j < 8; ++j) {
      int e = ks * 32 + e0 + j;
      float f = whh[(size_t)out * E + e];
      short h = f2bf(f);
      hi[j] = h;
      lo[j] = f2bf(f - bf2f(h));
    }
    size_t base = ((size_t)(ot * 2 + ks) * 2) * 512 + (size_t)l * 8;
    *(short8v*)(wp + base) = hi;
    *(short8v*)(wp + base + 512) = lo;
  }
}

// ---------------- MFMA bmm: out[hb][n][e] = sum_m A[n][m] X[hb][m][e] ----------------
__global__ __launch_bounds__(256) void bmmM_kernel(const short* __restrict__ ap,
                                                   const short* __restrict__ xp,
                                                   float* __restrict__ out) {
  int bid = blockIdx.x;
  int x8 = bid & 7, q = bid >> 3;
  int nt = q % 21, hbhi = q / 21;
  int hb = hbhi * 8 + x8;
  int tid = threadIdx.x, w = tid >> 6, l = tid & 63;
  const short8v* apf = (const short8v*)ap;
  const short8v* xpf = (const short8v*)(xp + (((size_t)hb * 4 + w) * 11) * 1024);
  f32x4 acc = {0.f, 0.f, 0.f, 0.f};
#pragma unroll
  for (int ks = 0; ks < 11; ++ks) {
    short8v ah = apf[((nt * 11 + ks) * 2 + 0) * 64 + l];
    short8v al = apf[((nt * 11 + ks) * 2 + 1) * 64 + l];
    short8v xh = xpf[(ks * 2 + 0) * 64 + l];
    short8v xl = xpf[(ks * 2 + 1) * 64 + l];
    acc = __builtin_amdgcn_mfma_f32_16x16x32_bf16(ah, xh, acc, 0, 0, 0);
    acc = __builtin_amdgcn_mfma_f32_16x16x32_bf16(ah, xl, acc, 0, 0, 0);
    acc = __builtin_amdgcn_mfma_f32_16x16x32_bf16(al, xh, acc, 0, 0, 0);
  }
  int row = nt * 16 + (l >> 4) * 4, col = w * 16 + (l & 15);
  float* o = out + (size_t)hb * N * E;
#pragma unroll
  for (int r = 0; r < 4; ++r)
    if (row + r < N) o[(size_t)(row + r) * E + col] = acc[r];
}

// ---------------- pack key into MFMA B-fragments (hi/lo bf16 split) ----------------
__global__ __launch_bounds__(128) void kpack_kernel(const float* __restrict__ memory,
                                                    short* __restrict__ kp) {
  int idx = blockIdx.x;          // (hop*B+b)*21 + ct
  int ct = idx % 21, hb = idx / 21;
  int tid = threadIdx.x, ks = tid >> 6, l = tid & 63;
  int m = ct * 16 + (l & 15);
  int e0 = ks * 32 + (l >> 4) * 8;
  short8v hi, lo;
  if (m < N) {
    const float* p = memory + ((size_t)hb * N + m) * E + e0;
#pragma unroll
    for (int j = 0; j < 8; ++j) {
      float f = p[j];
      short h = f2bf(f);
      hi[j] = h;
      lo[j] = f2bf(f - bf2f(h));
    }
  } else {
#pragma unroll
    for (int j = 0; j < 8; ++j) { hi[j] = 0; lo[j] = 0; }
  }
  size_t base = ((size_t)idx * 2 + ks) * 1024 + (size_t)l * 8;
  *(short8v*)(kp + base) = hi;
  *(short8v*)(kp + base + 512) = lo;
}

// ================= persistent step kernel (per-rt group arrival counters) =================
__global__ __launch_bounds__(512, 4) void step_kernel(
    const float* __restrict__ hidden,
    const float* __restrict__ kms,      // 3*BNE
    const short* __restrict__ kp,       // per-hop stride B*21*2048
    const short* __restrict__ zp,       // per-hop stride B*4*11*1024
    const float* __restrict__ C0,       // 3*BNE
    float* __restrict__ statsb,         // 36*STST, zeroed
    const float* __restrict__ gamma, const float* __restrict__ beta,
    const float* __restrict__ outw, const float* __restrict__ outb,
    const float* __restrict__ wih, const short* __restrict__ wp,
    const float* __restrict__ bih, const float* __restrict__ bhh,
    unsigned* __restrict__ arr,         // 36*11 counters, each on own 128B line
    float* __restrict__ dout) {
  int bid = blockIdx.x;
  int x8 = bid & 7, q = bid >> 3;            // XCD swizzle: same-b blocks share XCD
  int rt = q % 11, bhi = q / 11;
  int b = bhi * 8 + x8;
  int n0 = rt * 32, nrows = min(32, N - n0);
  int tid = threadIdx.x, w = tid >> 6, l = tid & 63;
  int g = l >> 4;
  size_t rowbase = (size_t)b * N + n0;
  auto ctr = [&](int t, int h) { return arr + ((size_t)(t * 3 + h) * 11 + rt) * 32; };

  __shared__ float uT[32][68];
  __shared__ float hT[32][68];
  __shared__ float gpreL[32][68];
  __shared__ float rowred[32][8];
  __shared__ float rmax[32], rsinv[32];
  __shared__ float pvL[32], sentL[3][32], owL[2][32];
  __shared__ __align__(16) char arenaRaw[25600];  // union: pb[32][360] bf16 | gh[32][200] f32
  short (*pb)[PBSTR] = (short (*)[PBSTR])arenaRaw;
  float (*ghL)[200] = (float (*)[200])arenaRaw;

  // init
#pragma unroll
  for (int rr = 0; rr < 4; ++rr) {
    int r = w * 4 + rr;
    hT[r][l] = (r < nrows) ? hidden[(rowbase + r) * E + l] : 0.f;
    if (l == 0) pvL[r] = 0.f;
  }
  float wi0 = wih[l], wi1 = wih[64 + l], wi2 = wih[128 + l];
  float bi0 = bih[l], bi1 = bih[64 + l], bi2 = bih[128 + l];
  float bh0 = bhh[l], bh1 = bhh[64 + l], bh2 = bhh[128 + l];
  float owv = outw[l];
  float ob = outb[0];
  __syncthreads();

  for (int t = 0; t < S; ++t) {
    // ---- finish of step t-1 (wait for its hop-2 stats group) ----
    if (t > 0) {
      group_wait(ctr(t - 1, 2), 32);
      const float* st2 = statsb + (size_t)((t - 1) * 3 + 2) * STST;
#pragma unroll
      for (int rr = 0; rr < 4; ++rr) {
        int r = w * 4 + rr, n = n0 + r;
        if (r < nrows) {
          float m = agent_loadf(&st2[n]) * (1.f / 2048.f);
          float var = agent_loadf(&st2[N + n]) * (1.f / 2048.f) - m * m;
          float rstd = rsqrtf(var + 1e-5f);
          float o = (gpreL[r][l] - m) * rstd * gamma[2 * N + n] + beta[2 * N + n];
          float tt = o * owv;
#pragma unroll
          for (int off = 32; off; off >>= 1) tt += __shfl_xor(tt, off);
          float v = ob + sentL[0][r] * owL[0][r] + sentL[1][r] * owL[1][r] + sentL[2][r] * tt;
          if (l == 0) {
            dout[((size_t)b * S + (t - 1)) * N + n] = v;
            pvL[r] = v;
          }
        }
      }
      __syncthreads();
    }
    // ---- GRU: gh = hT @ whh^T via MFMA ----
    short8v hah[2][2], hal[2][2];
    {
      int arow = l & 15, ak = g * 8;
#pragma unroll
      for (int mt = 0; mt < 2; ++mt)
#pragma unroll
        for (int ks = 0; ks < 2; ++ks) {
          const float* p = &hT[mt * 16 + arow][ks * 32 + ak];
          short8v h, lo;
#pragma unroll
          for (int j = 0; j < 8; ++j) {
            float f = p[j];
            short hh = f2bf(f);
            h[j] = hh;
            lo[j] = f2bf(f - bf2f(hh));
          }
          hah[mt][ks] = h; hal[mt][ks] = lo;
        }
    }
    const short8v* wpf = (const short8v*)wp;
#pragma unroll
    for (int i = 0; i < 3; ++i) {
      int idx = w * 3 + i;          // 24 tiles: mt*12 + ot
      int mt = idx / 12, ot = idx % 12;
      f32x4 acc = {0.f, 0.f, 0.f, 0.f};
#pragma unroll
      for (int ks = 0; ks < 2; ++ks) {
        short8v wh = wpf[((ot * 2 + ks) * 2 + 0) * 64 + l];
        short8v wl = wpf[((ot * 2 + ks) * 2 + 1) * 64 + l];
        acc = __builtin_amdgcn_mfma_f32_16x16x32_bf16(hah[mt][ks], wh, acc, 0, 0, 0);
        acc = __builtin_amdgcn_mfma_f32_16x16x32_bf16(hah[mt][ks], wl, acc, 0, 0, 0);
        acc = __builtin_amdgcn_mfma_f32_16x16x32_bf16(hal[mt][ks], wh, acc, 0, 0, 0);
      }
      int row0 = mt * 16 + g * 4, col = ot * 16 + (l & 15);
#pragma unroll
      for (int r = 0; r < 4; ++r) ghL[row0 + r][col] = acc[r];
    }
    __syncthreads();
    // gate combine
#pragma unroll
    for (int rr = 0; rr < 4; ++rr) {
      int r = w * 4 + rr;
      float hv = hT[r][l];
      float g0 = ghL[r][l] + bh0;
      float g1 = ghL[r][64 + l] + bh1;
      float g2 = ghL[r][128 + l] + bh2;
      float pv = pvL[r];
      float i0 = pv * wi0 + bi0, i1 = pv * wi1 + bi1, i2 = pv * wi2 + bi2;
      float rg = 1.f / (1.f + expf(-(i0 + g0)));
      float zg = 1.f / (1.f + expf(-(i1 + g1)));
      float nn = tanhf(i2 + rg * g2);
      float hn = (1.f - zg) * nn + zg * hv;
      if (r >= nrows) hn = 0.f;
      hT[r][l] = hn;
      uT[r][l] = hn;
    }
    __syncthreads();
    // re-zero pb pad cols (clobbered by ghL)
    for (int idx2 = tid; idx2 < 32 * (PBSTR - 336); idx2 += 512) {
      int r = idx2 / (PBSTR - 336), c = idx2 - r * (PBSTR - 336);
      pb[r][336 + c] = 0;
    }
    __syncthreads();
    // ---- hops ----
    for (int h = 0; h < 3; ++h) {
      if (h > 0) {  // bnapply of hop h-1: wait for its stats group first
        group_wait(ctr(t, h - 1), 32);
        const float* stp = statsb + (size_t)(t * 3 + h - 1) * STST;
        const float* gm = gamma + (h - 1) * N;
        const float* bt = beta + (h - 1) * N;
#pragma unroll
        for (int rr = 0; rr < 4; ++rr) {
          int r = w * 4 + rr, n = n0 + r;
          if (r < nrows) {
            float m = agent_loadf(&stp[n]) * (1.f / 2048.f);
            float var = agent_loadf(&stp[N + n]) * (1.f / 2048.f) - m * m;
            float rstd = rsqrtf(var + 1e-5f);
            float o = (gpreL[r][l] - m) * rstd * gm[n] + bt[n];
            uT[r][l] += o;
            float tt = o * owv;
#pragma unroll
            for (int off = 32; off; off >>= 1) tt += __shfl_xor(tt, off);
            if (l == 0) owL[h - 1][r] = tt;
          }
        }
        __syncthreads();
      }
      // sentinel
      const float* kmsH = kms + (size_t)h * BNE;
#pragma unroll
      for (int rr = 0; rr < 4; ++rr) {
        int r = w * 4 + rr;
        if (r < nrows) {
          float v = uT[r][l] * kmsH[(rowbase + r) * E + l];
#pragma unroll
          for (int off = 32; off; off >>= 1) v += __shfl_xor(v, off);
          if (l == 0) sentL[h][r] = v * SCALE_INV;
        }
      }
      // A fragments from uT (hi/lo)
      short8v ah[2][2], al[2][2];
      {
        int arow = l & 15, ak = g * 8;
#pragma unroll
        for (int mt = 0; mt < 2; ++mt)
#pragma unroll
          for (int ks = 0; ks < 2; ++ks) {
            const float* p = &uT[mt * 16 + arow][ks * 32 + ak];
            short8v hh_, lo_;
#pragma unroll
            for (int j = 0; j < 8; ++j) {
              float f = p[j];
              short hh = f2bf(f);
              hh_[j] = hh;
              lo_[j] = f2bf(f - bf2f(hh));
            }
            ah[mt][ks] = hh_; al[mt][ks] = lo_;
          }
      }
      // energy
      const short8v* kpb = (const short8v*)(kp + ((size_t)h * B + b) * 21 * 2048);
      f32x4 acc0[3], acc1[3];
#pragma unroll
      for (int i = 0; i < 3; ++i) {
        acc0[i] = (f32x4){0.f, 0.f, 0.f, 0.f};
        acc1[i] = (f32x4){0.f, 0.f, 0.f, 0.f};
        int ct = w + 8 * i;
        if (ct < 21) {
          short8v bh0v = kpb[(ct * 4 + 0) * 64 + l];
          short8v bl0v = kpb[(ct * 4 + 1) * 64 + l];
          short8v bh1v = kpb[(ct * 4 + 2) * 64 + l];
          short8v bl1v = kpb[(ct * 4 + 3) * 64 + l];
          f32x4 a0 = acc0[i], a1 = acc1[i];
          a0 = __builtin_amdgcn_mfma_f32_16x16x32_bf16(ah[0][0], bh0v, a0, 0, 0, 0);
          a0 = __builtin_amdgcn_mfma_f32_16x16x32_bf16(ah[0][0], bl0v, a0, 0, 0, 0);
          a0 = __builtin_amdgcn_mfma_f32_16x16x32_bf16(al[0][0], bh0v, a0, 0, 0, 0);
          a0 = __builtin_amdgcn_mfma_f32_16x16x32_bf16(ah[0][1], bh1v, a0, 0, 0, 0);
          a0 = __builtin_amdgcn_mfma_f32_16x16x32_bf16(ah[0][1], bl1v, a0, 0, 0, 0);
          a0 = __builtin_amdgcn_mfma_f32_16x16x32_bf16(al[0][1], bh1v, a0, 0, 0, 0);
          a1 = __builtin_amdgcn_mfma_f32_16x16x32_bf16(ah[1][0], bh0v, a1, 0, 0, 0);
          a1 = __builtin_amdgcn_mfma_f32_16x16x32_bf16(ah[1][0], bl0v, a1, 0, 0, 0);
          a1 = __builtin_amdgcn_mfma_f32_16x16x32_bf16(al[1][0], bh0v, a1, 0, 0, 0);
          a1 = __builtin_amdgcn_mfma_f32_16x16x32_bf16(ah[1][1], bh1v, a1, 0, 0, 0);
          a1 = __builtin_amdgcn_mfma_f32_16x16x32_bf16(ah[1][1], bl1v, a1, 0, 0, 0);
          a1 = __builtin_amdgcn_mfma_f32_16x16x32_bf16(al[1][1], bh1v, a1, 0, 0, 0);
          acc0[i] = a0; acc1[i] = a1;
        }
      }
      // row max
      {
        float m0[4], m1[4];
#pragma unroll
        for (int r = 0; r < 4; ++r) {
          float a = -1e30f, c = -1e30f;
#pragma unroll
          for (int i = 0; i < 3; ++i)
            if (w + 8 * i < 21) { a = fmaxf(a, acc0[i][r]); c = fmaxf(c, acc1[i][r]); }
#pragma unroll
          for (int off = 1; off < 16; off <<= 1) {
            a = fmaxf(a, __shfl_xor(a, off));
            c = fmaxf(c, __shfl_xor(c, off));
          }
          m0[r] = a; m1[r] = c;
        }
        if ((l & 15) == 0) {
#pragma unroll
          for (int r = 0; r < 4; ++r) {
            rowred[g * 4 + r][w] = m0[r];
            rowred[16 + g * 4 + r][w] = m1[r];
          }
        }
      }
      __syncthreads();
      if (tid < 32) {
        float a = rowred[tid][0];
#pragma unroll
        for (int j = 1; j < 8; ++j) a = fmaxf(a, rowred[tid][j]);
        rmax[tid] = a;
      }
      __syncthreads();
      // exp + bf16 + partial sums
      {
        float mx0[4], mx1[4], s0[4], s1[4];
#pragma unroll
        for (int r = 0; r < 4; ++r) {
          mx0[r] = rmax[g * 4 + r]; mx1[r] = rmax[16 + g * 4 + r];
          s0[r] = 0.f; s1[r] = 0.f;
        }
#pragma unroll
        for (int i = 0; i < 3; ++i) {
          int ct = w + 8 * i;
          if (ct < 21) {
            int col = ct * 16 + (l & 15);
            bool valid = col < N;
#pragma unroll
            for (int r = 0; r < 4; ++r) {
              short pv0 = 0, pv1 = 0;
              if (valid) {
                pv0 = f2bf(expf((acc0[i][r] - mx0[r]) * SCALE_INV));
                pv1 = f2bf(expf((acc1[i][r] - mx1[r]) * SCALE_INV));
                s0[r] += bf2f(pv0);
                s1[r] += bf2f(pv1);
              }
              pb[g * 4 + r][col] = pv0;
              pb[16 + g * 4 + r][col] = pv1;
            }
          }
        }
#pragma unroll
        for (int r = 0; r < 4; ++r) {
#pragma unroll
          for (int off = 1; off < 16; off <<= 1) {
            s0[r] += __shfl_xor(s0[r], off);
            s1[r] += __shfl_xor(s1[r], off);
          }
        }
        if ((l & 15) == 0) {
#pragma unroll
          for (int r = 0; r < 4; ++r) {
            rowred[g * 4 + r][w] = s0[r];
            rowred[16 + g * 4 + r][w] = s1[r];
          }
        }
      }
      __syncthreads();
      if (tid < 32) {
        float s = 0.f;
#pragma unroll
        for (int j = 0; j < 8; ++j) s += rowred[tid][j];
        rsinv[tid] = 1.f / s;
      }
      __syncthreads();
      // PV
      int mt2 = w >> 2, et = w & 3;
      const short8v* zpb = (const short8v*)(zp + ((size_t)h * B + b) * 4 * 11 * 1024);
      f32x4 acc = {0.f, 0.f, 0.f, 0.f};
      {
        int arow = mt2 * 16 + (l & 15), ak = g * 8;
#pragma unroll
        for (int ks = 0; ks < 11; ++ks) {
          short8v a = *(const short8v*)&pb[arow][ks * 32 + ak];
          short8v zh = zpb[((et * 11 + ks) * 2 + 0) * 64 + l];
          short8v zl = zpb[((et * 11 + ks) * 2 + 1) * 64 + l];
          acc = __builtin_amdgcn_mfma_f32_16x16x32_bf16(a, zh, acc, 0, 0, 0);
          acc = __builtin_amdgcn_mfma_f32_16x16x32_bf16(a, zl, acc, 0, 0, 0);
        }
      }
      // epilogue: gpreL + stats atomics
      const float* C0h = C0 + (size_t)h * BNE;
      float* stc = statsb + (size_t)(t * 3 + h) * STST;
      int colA = et * 16 + (l & 15);
#pragma unroll
      for (int r = 0; r < 4; ++r) {
        int row = mt2 * 16 + g * 4 + r;
        float sval = 0.f, qval = 0.f;
        if (row < nrows) {
          size_t gi = (rowbase + row) * E + colA;
          float gA = acc[r] * rsinv[row] + C0h[gi];
          gpreL[row][colA] = gA;
          sval = gA; qval = gA * gA;
        }
#pragma unroll
        for (int off = 1; off < 16; off <<= 1) {
          sval += __shfl_xor(sval, off);
          qval += __shfl_xor(qval, off);
        }
        if ((l & 15) == 0 && row < nrows) {
          atomicAdd(&stc[n0 + row], sval);
          atomicAdd(&stc[N + n0 + row], qval);
        }
      }
      group_arrive(ctr(t, h));
    }
  }
  // ---- final finish (t = S-1) ----
  {
    group_wait(ctr(S - 1, 2), 32);
    const float* st2 = statsb + (size_t)((S - 1) * 3 + 2) * STST;
#pragma unroll
    for (int rr = 0; rr < 4; ++rr) {
      int r = w * 4 + rr, n = n0 + r;
      if (r < nrows) {
        float m = agent_loadf(&st2[n]) * (1.f / 2048.f);
        float var = agent_loadf(&st2[N + n]) * (1.f / 2048.f) - m * m;
        float rstd = rsqrtf(var + 1e-5f);
        float o = (gpreL[r][l] - m) * rstd * gamma[2 * N + n] + beta[2 * N + n];
        float tt = o * owv;
#pragma unroll
        for (int off = 32; off; off >>= 1) tt += __shfl_xor(tt, off);
        float v = ob + sentL[0][r] * owL[0][r] + sentL[1][r] * owL[1][r] + sentL[2][r] * tt;
        if (l == 0) dout[((size_t)b * S + (S - 1)) * N + n] = v;
      }
    }
  }
}

extern "C" void kernel_launch(void* const* d_in, const int* in_sizes, int n_in,
                              void* d_out, int out_size, void* d_ws, size_t ws_size,
                              hipStream_t stream) {
  const float* hidden   = (const float*)d_in[0];
  const float* supports = (const float*)d_in[1];
  const float* memory   = (const float*)d_in[3];
  const float* nv1      = (const float*)d_in[4];
  const float* nv2      = (const float*)d_in[5];
  const float* wih      = (const float*)d_in[6];
  const float* whh      = (const float*)d_in[7];
  const float* bih      = (const float*)d_in[8];
  const float* bhh      = (const float*)d_in[9];
  const float* sent_w   = (const float*)d_in[10];
  const float* gamma    = (const float*)d_in[11];
  const float* beta     = (const float*)d_in[12];
  const float* gw       = (const float*)d_in[13];
  const float* gb       = (const float*)d_in[14];
  const float* outw     = (const float*)d_in[15];
  const float* outb     = (const float*)d_in[16];
  float* out = (float*)d_out;
  float* ws  = (float*)d_ws;

  size_t o = 0;
  float* adp   = ws + o; o += 105632;
  float* kms   = ws + o; o += (size_t)3 * BNE;
  float* C0b   = ws + o; o += (size_t)3 * BNE;
  float* uni   = ws + o; o += (size_t)9 * BNE;  // Zb(3)+t1(3)+t2(3)
  float* Zb  = uni;
  float* t1b = uni + (size_t)3 * BNE;
  float* t2b = uni + (size_t)6 * BNE;
  short* kpackS = (short*)(ws + o); o += 2064384;   // 3*B*21*2*2*512 shorts
  short* zpackS = (short*)(ws + o); o += 2162688;   // 3*B*4*11*2*512 shorts
  short* apackS = (short*)(ws + o); o += 354816;    // 3*21*11*2*512 shorts
  short* wpackS = (short*)(ws + o); o += 12288;     // 12*2*2*512 shorts
  short* xp0    = (short*)(ws + o); o += 2162688;
  short* xp1    = (short*)(ws + o); o += 2162688;
  float* statsb = ws + o; o += (size_t)36 * STST;
  unsigned* arr = (unsigned*)(ws + o); o += (size_t)36 * 11 * 32;  // 396 counters, 128B apart

  hipMemsetAsync(statsb, 0, sizeof(float) * 36 * STST, stream);
  hipMemsetAsync(arr, 0, sizeof(unsigned) * 36 * 11 * 32, stream);

  adp_kernel<<<N, 256, 0, stream>>>(nv1, nv2, adp);
  rowmmA_kernel<<<672, 256, 0, stream>>>(memory, sent_w, gw, gb, kms, C0b);
  kpack_kernel<<<3 * B * 21, 128, 0, stream>>>(memory, kpackS);
  apack_kernel<<<63, 64, 0, stream>>>(supports, adp, apackS);
  wpack_kernel<<<12, 64, 0, stream>>>(whh, wpackS);
  zpack_kernel<<<3 * B * 4, 64, 0, stream>>>(memory + BNE, xp0);

  for (int a = 0; a < 3; ++a) {
    const short* apA = apackS + (size_t)a * 21 * 11 * 2 * 512;
    bmmM_kernel<<<96 * 21, 256, 0, stream>>>(apA, xp0, t1b);
    rowmmZ_kernel<<<672, 256, 0, stream>>>(t1b, gw, 2 * a + 1, Zb, (a > 0) ? 1 : 0);
    zpack_kernel<<<3 * B * 4, 64, 0, stream>>>(t1b, xp1);
    bmmM_kernel<<<96 * 21, 256, 0, stream>>>(apA, xp1, t2b);
    rowmmZ_kernel<<<672, 256, 0, stream>>>(t2b, gw, 2 * a + 2, Zb, 1);
  }
  zpack_kernel<<<3 * B * 4, 64, 0, stream>>>(Zb, zpackS);

  step_kernel<<<B * 11, 512, 0, stream>>>(hidden, kms, kpackS, zpackS, C0b, statsb,
                                          gamma, beta, outw, outb, wih, wpackS,
                                          bih, bhh, arr, out);
}